// Round 2
// baseline (5773.333 us; speedup 1.0000x reference)
//
#include <hip/hip_runtime.h>
#include <hip/hip_bf16.h>

#define NNODES 100000
#define NEDGES 1600000
#define NF 256
#define NH 128

// ---------------- degree count (atomic f32, values small & exact) ----------
__global__ __launch_bounds__(256)
void deg_kernel(const int* __restrict__ src, const int* __restrict__ dst,
                float* __restrict__ outdeg, float* __restrict__ indeg, int E) {
    int i = blockIdx.x * blockDim.x + threadIdx.x;
    int stride = gridDim.x * blockDim.x;
    for (int e = i; e < E; e += stride) {
        atomicAdd(&outdeg[src[e]], 1.0f);
        atomicAdd(&indeg[dst[e]], 1.0f);
    }
}

// deg -> rsqrt(max(deg,1)) in place, over both arrays (2N contiguous)
__global__ __launch_bounds__(256)
void norm_kernel(float* __restrict__ deg, int n) {
    int i = blockIdx.x * blockDim.x + threadIdx.x;
    if (i < n) deg[i] = rsqrtf(fmaxf(deg[i], 1.0f));
}

// ---------------- GEMM: C[i,j] = norm_s[i] * sum_k f(A[i,k]) * W[k,j] ------
// MODE 0: f = identity (layer 1, A = x, K = 256)
// MODE 1: f(a) = relu(a*norm_d[i] + bias[k]) (layer 2, A = agg1, K = 128)
template<int MODE>
__global__ __launch_bounds__(256)
void gemm_kernel(const float* __restrict__ A, const float* __restrict__ W,
                 const float* __restrict__ norm_s, const float* __restrict__ norm_d,
                 const float* __restrict__ bias, float* __restrict__ C,
                 int N, int K) {
    __shared__ float As[64][68];    // 64 rows x 64 k, pad 4 floats (16B-aligned)
    __shared__ float Ws[64][NH];    // 64 k x 128 cols
    const int tid = threadIdx.x;
    const int tx = tid & 15;        // 16 col-groups, cols tx + 16u
    const int ty = tid >> 4;        // 16 row-groups, rows ty*4 + r
    const int row0 = blockIdx.x * 64;
    float acc[4][8] = {};

    for (int k0 = 0; k0 < K; k0 += 64) {
        // load A tile: 64x64 floats = 1024 float4, 4 per thread
        #pragma unroll
        for (int p = 0; p < 4; ++p) {
            int f = p * 256 + tid;
            int r = f >> 4, c4 = f & 15;
            int grow = row0 + r;
            float4 v = make_float4(0.f, 0.f, 0.f, 0.f);
            if (grow < N) {
                v = ((const float4*)(A + (size_t)grow * K + k0))[c4];
                if (MODE == 1) {
                    float nd = norm_d[grow];
                    v.x = fmaxf(fmaf(v.x, nd, bias[k0 + c4*4 + 0]), 0.f);
                    v.y = fmaxf(fmaf(v.y, nd, bias[k0 + c4*4 + 1]), 0.f);
                    v.z = fmaxf(fmaf(v.z, nd, bias[k0 + c4*4 + 2]), 0.f);
                    v.w = fmaxf(fmaf(v.w, nd, bias[k0 + c4*4 + 3]), 0.f);
                }
            }
            *(float4*)&As[r][c4 * 4] = v;
        }
        // load W tile: 64x128 floats = 2048 float4, 8 per thread
        #pragma unroll
        for (int p = 0; p < 8; ++p) {
            int f = p * 256 + tid;
            int r = f >> 5, c4 = f & 31;
            float4 w = ((const float4*)(W + (size_t)(k0 + r) * NH))[c4];
            *(float4*)&Ws[r][c4 * 4] = w;
        }
        __syncthreads();
        #pragma unroll 8
        for (int kk = 0; kk < 64; ++kk) {
            float a[4], w[8];
            #pragma unroll
            for (int r = 0; r < 4; ++r) a[r] = As[ty*4 + r][kk];     // broadcast across tx
            #pragma unroll
            for (int u = 0; u < 8; ++u) w[u] = Ws[kk][tx + 16*u];    // conflict-free, broadcast across ty
            #pragma unroll
            for (int r = 0; r < 4; ++r)
                #pragma unroll
                for (int u = 0; u < 8; ++u)
                    acc[r][u] = fmaf(a[r], w[u], acc[r][u]);
        }
        __syncthreads();
    }
    #pragma unroll
    for (int r = 0; r < 4; ++r) {
        int gi = row0 + ty*4 + r;
        if (gi < N) {
            float s = norm_s[gi];
            float* crow = C + (size_t)gi * NH;
            #pragma unroll
            for (int u = 0; u < 8; ++u) crow[tx + 16*u] = acc[r][u] * s;
        }
    }
}

// ---------------- edge scatter-add: agg[dst] += m[src], 32 lanes/edge -------
__global__ __launch_bounds__(256)
void scatter_kernel(const float* __restrict__ m, const int* __restrict__ src,
                    const int* __restrict__ dst, float* __restrict__ agg, int E) {
    int t = blockIdx.x * 256 + threadIdx.x;
    int e = t >> 5;
    if (e >= E) return;
    int lane = t & 31;
    int s = src[e], d = dst[e];
    float4 v = ((const float4*)(m + (size_t)s * NH))[lane];
    float* o = agg + (size_t)d * NH + lane * 4;
    atomicAdd(o + 0, v.x);
    atomicAdd(o + 1, v.y);
    atomicAdd(o + 2, v.z);
    atomicAdd(o + 3, v.w);
}

// ---------------- final: out[i] = sum_j (agg2[i,j]*nd + b2[j]) * Wfc[j] + bfc
__global__ __launch_bounds__(256)
void final_kernel(const float* __restrict__ agg, const float* __restrict__ norm_d,
                  const float* __restrict__ b2, const float* __restrict__ Wfc,
                  const float* __restrict__ bfc, float* __restrict__ out, int N) {
    int w = (blockIdx.x * 256 + threadIdx.x) >> 6;   // one wave per node
    int lane = threadIdx.x & 63;
    if (w >= N) return;
    const float* row = agg + (size_t)w * NH;
    float nd = norm_d[w];
    float acc = 0.f;
    #pragma unroll
    for (int u = 0; u < 2; ++u) {
        int j = lane + 64 * u;
        acc = fmaf(fmaf(row[j], nd, b2[j]), Wfc[j], acc);
    }
    #pragma unroll
    for (int off = 32; off > 0; off >>= 1) acc += __shfl_down(acc, off);
    if (lane == 0) out[w] = acc + bfc[0];
}

extern "C" void kernel_launch(void* const* d_in, const int* in_sizes, int n_in,
                              void* d_out, int out_size, void* d_ws, size_t ws_size,
                              hipStream_t stream) {
    const float* x   = (const float*)d_in[0];
    const float* W1  = (const float*)d_in[1];
    const float* b1  = (const float*)d_in[2];
    const float* W2  = (const float*)d_in[3];
    const float* b2  = (const float*)d_in[4];
    const float* Wfc = (const float*)d_in[5];
    const float* bfc = (const float*)d_in[6];
    const int*   src = (const int*)d_in[7];
    const int*   dst = (const int*)d_in[8];
    float* out = (float*)d_out;

    const int N = NNODES, E = NEDGES;

    // workspace layout (f32): norm_s[N] | norm_d[N] | bufA[N*128] | bufB[N*128]
    float* norm_s = (float*)d_ws;
    float* norm_d = norm_s + N;
    float* bufA   = norm_d + N;
    float* bufB   = bufA + (size_t)N * NH;

    // degrees -> norms
    hipMemsetAsync(norm_s, 0, 2 * (size_t)N * sizeof(float), stream);
    deg_kernel<<<1024, 256, 0, stream>>>(src, dst, norm_s, norm_d, E);
    norm_kernel<<<(2 * N + 255) / 256, 256, 0, stream>>>(norm_s, 2 * N);

    // layer 1: m1 = (x * norm_s) @ W1 ; agg1 = scatter_add(m1[src] -> dst)
    gemm_kernel<0><<<(N + 63) / 64, 256, 0, stream>>>(x, W1, norm_s, nullptr, nullptr, bufA, N, NF);
    hipMemsetAsync(bufB, 0, (size_t)N * NH * sizeof(float), stream);
    scatter_kernel<<<(E * 32) / 256, 256, 0, stream>>>(bufA, src, dst, bufB, E);

    // layer 2: h1 = relu(agg1*norm_d + b1); m2 = (h1*norm_s) @ W2 ; agg2 = scatter
    gemm_kernel<1><<<(N + 63) / 64, 256, 0, stream>>>(bufB, W2, norm_s, norm_d, b1, bufA, N, NH);
    hipMemsetAsync(bufB, 0, (size_t)N * NH * sizeof(float), stream);
    scatter_kernel<<<(E * 32) / 256, 256, 0, stream>>>(bufA, src, dst, bufB, E);

    // output projection
    final_kernel<<<((size_t)N * 64 + 255) / 256, 256, 0, stream>>>(bufB, norm_d, b2, Wfc, bfc, out, N);
}

// Round 3
// 684.616 us; speedup vs baseline: 8.4329x; 8.4329x over previous
//
#include <hip/hip_runtime.h>
#include <hip/hip_bf16.h>

#define NNODES 100000
#define NEDGES 1600000
#define NF 256
#define NH 128
#define SCAN_ELEMS 1024
#define SCAN_NBLK ((NNODES + SCAN_ELEMS - 1) / SCAN_ELEMS)   // 98

// ---------------- histogram: int degree counts ------------------------------
__global__ __launch_bounds__(256)
void hist_kernel(const int* __restrict__ src, const int* __restrict__ dst,
                 int* __restrict__ cnt_out, int* __restrict__ cnt_in, int E) {
    int i = blockIdx.x * blockDim.x + threadIdx.x;
    int stride = gridDim.x * blockDim.x;
    for (int e = i; e < E; e += stride) {
        atomicAdd(&cnt_out[src[e]], 1);
        atomicAdd(&cnt_in[dst[e]], 1);
    }
}

// ---------------- norms from int degrees ------------------------------------
__global__ __launch_bounds__(256)
void norms_kernel(const int* __restrict__ cnt_out, const int* __restrict__ cnt_in,
                  float* __restrict__ ns, float* __restrict__ nd, int n) {
    int i = blockIdx.x * blockDim.x + threadIdx.x;
    if (i < n) {
        ns[i] = rsqrtf((float)max(cnt_out[i], 1));
        nd[i] = rsqrtf((float)max(cnt_in[i], 1));
    }
}

// ---------------- 3-pass exclusive scan over cnt_in -> row_ptr --------------
__global__ __launch_bounds__(256)
void scanA_kernel(const int* __restrict__ cnt, int* __restrict__ pre,
                  int* __restrict__ bsum, int n) {
    __shared__ int tsum[256];
    int b = blockIdx.x, t = threadIdx.x;
    int base = b * SCAN_ELEMS + t * 4;
    int v[4]; int s = 0;
    #pragma unroll
    for (int k = 0; k < 4; ++k) { int idx = base + k; v[k] = (idx < n) ? cnt[idx] : 0; s += v[k]; }
    tsum[t] = s;
    __syncthreads();
    for (int off = 1; off < 256; off <<= 1) {
        int val = (t >= off) ? tsum[t - off] : 0;
        __syncthreads();
        tsum[t] += val;
        __syncthreads();
    }
    int run = (t == 0) ? 0 : tsum[t - 1];
    #pragma unroll
    for (int k = 0; k < 4; ++k) { int idx = base + k; if (idx < n) pre[idx] = run; run += v[k]; }
    if (t == 255) bsum[b] = tsum[255];
}

__global__ void scanB_kernel(int* __restrict__ bsum, int nb, int* __restrict__ row_ptr) {
    if (threadIdx.x == 0 && blockIdx.x == 0) {
        int run = 0;
        for (int i = 0; i < nb; ++i) { int v = bsum[i]; bsum[i] = run; run += v; }
        row_ptr[NNODES] = NEDGES;
    }
}

__global__ __launch_bounds__(256)
void scanC_kernel(int* __restrict__ pre, const int* __restrict__ bsum, int n) {
    int add = bsum[blockIdx.x];
    int base = blockIdx.x * SCAN_ELEMS + threadIdx.x;
    #pragma unroll
    for (int k = 0; k < 4; ++k) { int idx = base + k * 256; if (idx < n) pre[idx] += add; }
}

// ---------------- cursor = row_ptr[0:N) -------------------------------------
__global__ __launch_bounds__(256)
void copy_kernel(const int* __restrict__ a, int* __restrict__ b, int n) {
    int i = blockIdx.x * blockDim.x + threadIdx.x;
    if (i < n) b[i] = a[i];
}

// ---------------- bucket fill: col[pos] = src, buckets by dst ---------------
__global__ __launch_bounds__(256)
void fill_kernel(const int* __restrict__ src, const int* __restrict__ dst,
                 int* __restrict__ cursor, int* __restrict__ col, int E) {
    int i = blockIdx.x * blockDim.x + threadIdx.x;
    int stride = gridDim.x * blockDim.x;
    for (int e = i; e < E; e += stride) {
        int p = atomicAdd(&cursor[dst[e]], 1);
        col[p] = src[e];
    }
}

// ---------------- GEMM: C[i,j] = norm_s[i] * sum_k f(A[i,k]) * W[k,j] ------
// MODE 0: f = identity (layer 1, A = x, K = 256)
// MODE 1: f(a) = relu(a*norm_d[i] + bias[k]) (layer 2, A = agg1, K = 128)
template<int MODE>
__global__ __launch_bounds__(256)
void gemm_kernel(const float* __restrict__ A, const float* __restrict__ W,
                 const float* __restrict__ norm_s, const float* __restrict__ norm_d,
                 const float* __restrict__ bias, float* __restrict__ C,
                 int N, int K) {
    __shared__ float As[64][68];
    __shared__ float Ws[64][NH];
    const int tid = threadIdx.x;
    const int tx = tid & 15;
    const int ty = tid >> 4;
    const int row0 = blockIdx.x * 64;
    float acc[4][8] = {};

    for (int k0 = 0; k0 < K; k0 += 64) {
        #pragma unroll
        for (int p = 0; p < 4; ++p) {
            int f = p * 256 + tid;
            int r = f >> 4, c4 = f & 15;
            int grow = row0 + r;
            float4 v = make_float4(0.f, 0.f, 0.f, 0.f);
            if (grow < N) {
                v = ((const float4*)(A + (size_t)grow * K + k0))[c4];
                if (MODE == 1) {
                    float nd = norm_d[grow];
                    v.x = fmaxf(fmaf(v.x, nd, bias[k0 + c4*4 + 0]), 0.f);
                    v.y = fmaxf(fmaf(v.y, nd, bias[k0 + c4*4 + 1]), 0.f);
                    v.z = fmaxf(fmaf(v.z, nd, bias[k0 + c4*4 + 2]), 0.f);
                    v.w = fmaxf(fmaf(v.w, nd, bias[k0 + c4*4 + 3]), 0.f);
                }
            }
            *(float4*)&As[r][c4 * 4] = v;
        }
        #pragma unroll
        for (int p = 0; p < 8; ++p) {
            int f = p * 256 + tid;
            int r = f >> 5, c4 = f & 31;
            float4 w = ((const float4*)(W + (size_t)(k0 + r) * NH))[c4];
            *(float4*)&Ws[r][c4 * 4] = w;
        }
        __syncthreads();
        #pragma unroll 8
        for (int kk = 0; kk < 64; ++kk) {
            float a[4], w[8];
            #pragma unroll
            for (int r = 0; r < 4; ++r) a[r] = As[ty*4 + r][kk];
            #pragma unroll
            for (int u = 0; u < 8; ++u) w[u] = Ws[kk][tx + 16*u];
            #pragma unroll
            for (int r = 0; r < 4; ++r)
                #pragma unroll
                for (int u = 0; u < 8; ++u)
                    acc[r][u] = fmaf(a[r], w[u], acc[r][u]);
        }
        __syncthreads();
    }
    #pragma unroll
    for (int r = 0; r < 4; ++r) {
        int gi = row0 + ty*4 + r;
        if (gi < N) {
            float s = norm_s[gi];
            float* crow = C + (size_t)gi * NH;
            #pragma unroll
            for (int u = 0; u < 8; ++u) crow[tx + 16*u] = acc[r][u] * s;
        }
    }
}

// ---------------- CSR gather: one wave per node -----------------------------
// FUSED=0: agg[w] = sum_{e in bucket(w)} m[col[e]]            (write 512B/node)
// FUSED=1: out[w] = dot(agg*nd + b2, Wfc) + bfc               (write 4B/node)
template<int FUSED>
__global__ __launch_bounds__(256)
void gather_kernel(const float* __restrict__ m, const int* __restrict__ row_ptr,
                   const int* __restrict__ col, const float* __restrict__ norm_d,
                   const float* __restrict__ b2, const float* __restrict__ Wfc,
                   const float* __restrict__ bfc, float* __restrict__ outbuf, int N) {
    int w = (blockIdx.x * 256 + threadIdx.x) >> 6;
    int lane = threadIdx.x & 63;
    if (w >= N) return;
    int beg = row_ptr[w], end = row_ptr[w + 1];
    float2 acc = make_float2(0.f, 0.f);
    int i = beg;
    // unroll-by-2 for load-level parallelism
    for (; i + 1 < end; i += 2) {
        int s0 = col[i], s1 = col[i + 1];
        float2 v0 = ((const float2*)(m + (size_t)s0 * NH))[lane];
        float2 v1 = ((const float2*)(m + (size_t)s1 * NH))[lane];
        acc.x += v0.x + v1.x;
        acc.y += v0.y + v1.y;
    }
    if (i < end) {
        float2 v = ((const float2*)(m + (size_t)col[i] * NH))[lane];
        acc.x += v.x; acc.y += v.y;
    }
    if (FUSED == 0) {
        ((float2*)(outbuf + (size_t)w * NH))[lane] = acc;
    } else {
        float nd = norm_d[w];
        float p = fmaf(fmaf(acc.x, nd, b2[2*lane]), Wfc[2*lane],
                       fmaf(acc.y, nd, b2[2*lane+1]) * Wfc[2*lane+1]);
        #pragma unroll
        for (int off = 32; off > 0; off >>= 1) p += __shfl_down(p, off);
        if (lane == 0) outbuf[w] = p + bfc[0];
    }
}

extern "C" void kernel_launch(void* const* d_in, const int* in_sizes, int n_in,
                              void* d_out, int out_size, void* d_ws, size_t ws_size,
                              hipStream_t stream) {
    const float* x   = (const float*)d_in[0];
    const float* W1  = (const float*)d_in[1];
    const float* b1  = (const float*)d_in[2];
    const float* W2  = (const float*)d_in[3];
    const float* b2  = (const float*)d_in[4];
    const float* Wfc = (const float*)d_in[5];
    const float* bfc = (const float*)d_in[6];
    const int*   src = (const int*)d_in[7];
    const int*   dst = (const int*)d_in[8];
    float* out = (float*)d_out;

    const int N = NNODES, E = NEDGES;

    // workspace layout
    float* norm_s  = (float*)d_ws;                    // N
    float* norm_d  = norm_s + N;                      // N
    float* bufA    = norm_d + N;                      // N*NH
    float* bufB    = bufA + (size_t)N * NH;           // N*NH
    int*   cnt_out = (int*)(bufB + (size_t)N * NH);   // N
    int*   cnt_in  = cnt_out + N;                     // N (reused as cursor)
    int*   row_ptr = cnt_in + N;                      // N+1
    int*   col     = row_ptr + (N + 1);               // E
    int*   bsum    = col + E;                         // SCAN_NBLK

    // ---- CSR build + norms (~100 us) ----
    hipMemsetAsync(cnt_out, 0, 2 * (size_t)N * sizeof(int), stream);
    hist_kernel<<<1024, 256, 0, stream>>>(src, dst, cnt_out, cnt_in, E);
    norms_kernel<<<(N + 255) / 256, 256, 0, stream>>>(cnt_out, cnt_in, norm_s, norm_d, N);
    scanA_kernel<<<SCAN_NBLK, 256, 0, stream>>>(cnt_in, row_ptr, bsum, N);
    scanB_kernel<<<1, 64, 0, stream>>>(bsum, SCAN_NBLK, row_ptr);
    scanC_kernel<<<SCAN_NBLK, 256, 0, stream>>>(row_ptr, bsum, N);
    copy_kernel<<<(N + 255) / 256, 256, 0, stream>>>(row_ptr, cnt_in, N);  // cursor
    fill_kernel<<<(E + 255) / 256, 256, 0, stream>>>(src, dst, cnt_in, col, E);

    // ---- layer 1: m1 = (x*ns)@W1 -> bufA ; agg1 = gather -> bufB ----
    gemm_kernel<0><<<(N + 63) / 64, 256, 0, stream>>>(x, W1, norm_s, nullptr, nullptr, bufA, N, NF);
    gather_kernel<0><<<(N * 64) / 256, 256, 0, stream>>>(bufA, row_ptr, col, nullptr, nullptr, nullptr, nullptr, bufB, N);

    // ---- layer 2: m2 = (relu(agg1*nd+b1)*ns)@W2 -> bufA ; fused gather+fc -> out ----
    gemm_kernel<1><<<(N + 63) / 64, 256, 0, stream>>>(bufB, W2, norm_s, norm_d, b1, bufA, N, NH);
    gather_kernel<1><<<(N * 64) / 256, 256, 0, stream>>>(bufA, row_ptr, col, norm_d, b2, Wfc, bfc, out, N);
}

// Round 4
// 484.745 us; speedup vs baseline: 11.9101x; 1.4123x over previous
//
#include <hip/hip_runtime.h>
#include <hip/hip_bf16.h>

#define NNODES 100000
#define NEDGES 1600000
#define NF 256
#define NH 128
#define SCAN_ELEMS 1024
#define SCAN_NBLK ((NNODES + SCAN_ELEMS - 1) / SCAN_ELEMS)   // 98

typedef _Float16 half4v __attribute__((ext_vector_type(4)));
typedef _Float16 half8v __attribute__((ext_vector_type(8)));
typedef float floatx16 __attribute__((ext_vector_type(16)));

// k-permutation within each 16-block so MFMA f16 fragments (k = g*4 + (j&3) + 8*(j>>2))
// are 8 contiguous halves in storage. perm: [0,1,2,3, 8,9,10,11, 4,5,6,7, 12,13,14,15]
__device__ __forceinline__ int pos16(int k) {        // logical k (0..15) -> storage pos
    return (((k >> 2) & 1) << 3) + (k & 3) + (((k >> 3) & 1) << 2);
}
__device__ __forceinline__ int ipos16(int p) {       // storage pos -> logical k
    int g = (p >> 3) & 1, j = p & 7;
    return g * 4 + (j & 3) + ((j >> 2) << 3);
}

__device__ __forceinline__ float2 h2f2(unsigned u) {
    union { unsigned u; _Float16 h[2]; } c; c.u = u;
    return make_float2((float)c.h[0], (float)c.h[1]);
}

// ---------------- histogram: int degree counts ------------------------------
__global__ __launch_bounds__(256)
void hist_kernel(const int* __restrict__ src, const int* __restrict__ dst,
                 int* __restrict__ cnt_out, int* __restrict__ cnt_in, int E) {
    int i = blockIdx.x * blockDim.x + threadIdx.x;
    int stride = gridDim.x * blockDim.x;
    for (int e = i; e < E; e += stride) {
        atomicAdd(&cnt_out[src[e]], 1);
        atomicAdd(&cnt_in[dst[e]], 1);
    }
}

__global__ __launch_bounds__(256)
void norms_kernel(const int* __restrict__ cnt_out, const int* __restrict__ cnt_in,
                  float* __restrict__ ns, float* __restrict__ nd, int n) {
    int i = blockIdx.x * blockDim.x + threadIdx.x;
    if (i < n) {
        ns[i] = rsqrtf((float)max(cnt_out[i], 1));
        nd[i] = rsqrtf((float)max(cnt_in[i], 1));
    }
}

// ---------------- 3-pass exclusive scan over cnt_in -> row_ptr --------------
__global__ __launch_bounds__(256)
void scanA_kernel(const int* __restrict__ cnt, int* __restrict__ pre,
                  int* __restrict__ bsum, int n) {
    __shared__ int tsum[256];
    int b = blockIdx.x, t = threadIdx.x;
    int base = b * SCAN_ELEMS + t * 4;
    int v[4]; int s = 0;
    #pragma unroll
    for (int k = 0; k < 4; ++k) { int idx = base + k; v[k] = (idx < n) ? cnt[idx] : 0; s += v[k]; }
    tsum[t] = s;
    __syncthreads();
    for (int off = 1; off < 256; off <<= 1) {
        int val = (t >= off) ? tsum[t - off] : 0;
        __syncthreads();
        tsum[t] += val;
        __syncthreads();
    }
    int run = (t == 0) ? 0 : tsum[t - 1];
    #pragma unroll
    for (int k = 0; k < 4; ++k) { int idx = base + k; if (idx < n) pre[idx] = run; run += v[k]; }
    if (t == 255) bsum[b] = tsum[255];
}

__global__ void scanB_kernel(int* __restrict__ bsum, int nb, int* __restrict__ row_ptr) {
    if (threadIdx.x == 0 && blockIdx.x == 0) {
        int run = 0;
        for (int i = 0; i < nb; ++i) { int v = bsum[i]; bsum[i] = run; run += v; }
        row_ptr[NNODES] = NEDGES;
    }
}

__global__ __launch_bounds__(256)
void scanC_kernel(int* __restrict__ pre, const int* __restrict__ bsum, int n) {
    int add = bsum[blockIdx.x];
    int base = blockIdx.x * SCAN_ELEMS + threadIdx.x;
    #pragma unroll
    for (int k = 0; k < 4; ++k) { int idx = base + k * 256; if (idx < n) pre[idx] += add; }
}

__global__ __launch_bounds__(256)
void copy_kernel(const int* __restrict__ a, int* __restrict__ b, int n) {
    int i = blockIdx.x * blockDim.x + threadIdx.x;
    if (i < n) b[i] = a[i];
}

__global__ __launch_bounds__(256)
void fill_kernel(const int* __restrict__ src, const int* __restrict__ dst,
                 int* __restrict__ cursor, int* __restrict__ col, int E) {
    int i = blockIdx.x * blockDim.x + threadIdx.x;
    int stride = gridDim.x * blockDim.x;
    for (int e = i; e < E; e += stride) {
        int p = atomicAdd(&cursor[dst[e]], 1);
        col[p] = src[e];
    }
}

// ---------------- weight prep: transpose + k-permute to f16, permute vectors -
__global__ __launch_bounds__(256)
void wprep_kernel(const float* __restrict__ W1, const float* __restrict__ W2,
                  const float* __restrict__ b1, const float* __restrict__ b2,
                  const float* __restrict__ Wfc,
                  _Float16* __restrict__ Wt1, _Float16* __restrict__ Wt2,
                  float* __restrict__ b1p, float* __restrict__ b2p,
                  float* __restrict__ Wfcp) {
    int id = blockIdx.x * 256 + threadIdx.x;
    if (id < NF * NH) {                       // W1: [256][128] -> Wt1[n][perm(k)] f16
        int k = id >> 7, n = id & 127;
        Wt1[(size_t)n * NF + (k & ~15) + pos16(k & 15)] = (_Float16)W1[id];
    } else if (id < NF * NH + NH * NH) {      // W2: [128][128]
        int id2 = id - NF * NH;
        int k = id2 >> 7, n = id2 & 127;
        Wt2[(size_t)n * NH + (k & ~15) + pos16(k & 15)] = (_Float16)W2[id2];
    } else if (id < NF * NH + NH * NH + 3 * NH) {
        int id3 = id - NF * NH - NH * NH;
        int vec = id3 >> 7, pos = id3 & 127;
        int k = (pos & ~15) + ipos16(pos & 15);
        if (vec == 0) b1p[pos] = b1[k];
        else if (vec == 1) b2p[pos] = b2[k];
        else Wfcp[pos] = Wfc[k];
    }
}

// ---------------- MFMA GEMM: C = A @ W (+ row scale), f16 in/out ------------
// MODE 0: A = x (f32 [N][K], logical k order), C row scaled by norm_s, K=256
// MODE 1: A = f16 [N][K] perm-order (scales already folded), K=128
// Wt: f16 [128][K], transposed + k-permuted.  C: f16 [N][128], k-permuted cols.
template<int MODE>
__global__ __launch_bounds__(256)
void mfma_gemm(const void* __restrict__ Ain, const _Float16* __restrict__ Wt,
               const float* __restrict__ norm_s, _Float16* __restrict__ Cout,
               int N, int K) {
    __shared__ _Float16 As[128][40];   // 32 halves + 8 pad (80B row: bank-spread)
    __shared__ _Float16 Bs[128][40];
    __shared__ float ns_s[128];
    const int tid = threadIdx.x;
    const int l = tid & 63, w = tid >> 6;
    const int wr = w >> 1, wc = w & 1;           // 2x2 wave grid, 64x64 per wave
    const int row0 = blockIdx.x * 128;
    if (MODE == 0 && tid < 128) {
        int gr = row0 + tid;
        ns_s[tid] = (gr < N) ? norm_s[gr] : 0.f;
    }
    floatx16 acc[2][2] = {};

    for (int k0 = 0; k0 < K; k0 += 32) {
        if (MODE == 0) {
            const float* A = (const float*)Ain;
            #pragma unroll
            for (int p = 0; p < 4; ++p) {
                int f = p * 256 + tid;
                int r = f >> 3, c4 = f & 7;      // 8 float4 per row = 32 k
                int grow = row0 + r;
                float4 v = make_float4(0.f, 0.f, 0.f, 0.f);
                if (grow < N) v = ((const float4*)(A + (size_t)grow * K + k0))[c4];
                // permuted store base for logical k = c4*4..+3
                int base = ((c4 >> 2) << 4) + ((c4 & 1) << 3) + (((c4 >> 1) & 1) << 2);
                half4v h = { (_Float16)v.x, (_Float16)v.y, (_Float16)v.z, (_Float16)v.w };
                *(half4v*)&As[r][base] = h;
            }
        } else {
            const _Float16* A = (const _Float16*)Ain;
            #pragma unroll
            for (int p = 0; p < 2; ++p) {
                int f = p * 256 + tid;
                int r = f >> 2, c8 = f & 3;      // 4 x 8 halves per row
                int grow = row0 + r;
                half8v v = {0, 0, 0, 0, 0, 0, 0, 0};
                if (grow < N) v = *(const half8v*)(A + (size_t)grow * K + k0 + c8 * 8);
                *(half8v*)&As[r][c8 * 8] = v;
            }
        }
        #pragma unroll
        for (int p = 0; p < 2; ++p) {
            int f = p * 256 + tid;
            int n = f >> 2, c8 = f & 3;
            *(half8v*)&Bs[n][c8 * 8] = *(const half8v*)(Wt + (size_t)n * K + k0 + c8 * 8);
        }
        __syncthreads();
        #pragma unroll
        for (int kk = 0; kk < 2; ++kk) {
            half8v a[2], b[2];
            #pragma unroll
            for (int m = 0; m < 2; ++m)
                a[m] = *(const half8v*)&As[wr * 64 + m * 32 + (l & 31)][kk * 16 + (l >> 5) * 8];
            #pragma unroll
            for (int n = 0; n < 2; ++n)
                b[n] = *(const half8v*)&Bs[wc * 64 + n * 32 + (l & 31)][kk * 16 + (l >> 5) * 8];
            #pragma unroll
            for (int m = 0; m < 2; ++m)
                #pragma unroll
                for (int n = 0; n < 2; ++n)
                    acc[m][n] = __builtin_amdgcn_mfma_f32_32x32x16_f16(a[m], b[n], acc[m][n], 0, 0, 0);
        }
        __syncthreads();
    }

    // epilogue: D row = (r&3)+8*(r>>2)+4*(l>>5), col = l&31 (verified m74/m101 layout)
    const int cpos = pos16(l & 15);
    const int chi = ((l >> 4) & 1) << 4;
    #pragma unroll
    for (int m = 0; m < 2; ++m) {
        #pragma unroll
        for (int r = 0; r < 16; ++r) {
            int rloc = wr * 64 + m * 32 + (r & 3) + ((r >> 2) << 3) + ((l >> 5) << 2);
            int grow = row0 + rloc;
            if (grow < N) {
                float s = (MODE == 0) ? ns_s[rloc] : 1.0f;
                #pragma unroll
                for (int n = 0; n < 2; ++n) {
                    int colbase = wc * 64 + n * 32 + chi;
                    Cout[(size_t)grow * NH + colbase + cpos] = (_Float16)(acc[m][n][r] * s);
                }
            }
        }
    }
}

// ---------------- CSR gather over f16 perm-order rows, one wave per node ----
// FUSED=0: h = relu(acc*nd + b1p)*ns -> f16 perm-order row (GEMM2 operand)
// FUSED=1: out[w] = dot(acc*nd + b2p, Wfcp) + bfc
template<int FUSED>
__global__ __launch_bounds__(256)
void gatherh_kernel(const _Float16* __restrict__ m, const int* __restrict__ row_ptr,
                    const int* __restrict__ col, const float* __restrict__ norm_d,
                    const float* __restrict__ norm_s, const float* __restrict__ bvp,
                    const float* __restrict__ Wfcp, const float* __restrict__ bfc,
                    void* __restrict__ outbuf, int N) {
    int w = (blockIdx.x * 256 + threadIdx.x) >> 6;
    int lane = threadIdx.x & 63;
    if (w >= N) return;
    int beg = row_ptr[w], end = row_ptr[w + 1];
    const unsigned* mu = (const unsigned*)m;     // 64 uints (128 halves) per row
    float ax = 0.f, ay = 0.f;
    int i = beg;
    for (; i + 3 < end; i += 4) {
        unsigned u0 = mu[(size_t)col[i]     * 64 + lane];
        unsigned u1 = mu[(size_t)col[i + 1] * 64 + lane];
        unsigned u2 = mu[(size_t)col[i + 2] * 64 + lane];
        unsigned u3 = mu[(size_t)col[i + 3] * 64 + lane];
        float2 v0 = h2f2(u0), v1 = h2f2(u1), v2 = h2f2(u2), v3 = h2f2(u3);
        ax += (v0.x + v1.x) + (v2.x + v3.x);
        ay += (v0.y + v1.y) + (v2.y + v3.y);
    }
    for (; i < end; ++i) {
        float2 v = h2f2(mu[(size_t)col[i] * 64 + lane]);
        ax += v.x; ay += v.y;
    }
    float nd = norm_d[w];
    float2 bv = ((const float2*)bvp)[lane];
    if (FUSED == 0) {
        float ns = norm_s[w];
        float hx = fmaxf(fmaf(ax, nd, bv.x), 0.f) * ns;
        float hy = fmaxf(fmaf(ay, nd, bv.y), 0.f) * ns;
        union { unsigned u; _Float16 h[2]; } c;
        c.h[0] = (_Float16)hx; c.h[1] = (_Float16)hy;
        ((unsigned*)outbuf)[(size_t)w * 64 + lane] = c.u;
    } else {
        float2 wf = ((const float2*)Wfcp)[lane];
        float p = fmaf(ax, nd, bv.x) * wf.x + fmaf(ay, nd, bv.y) * wf.y;
        #pragma unroll
        for (int off = 32; off > 0; off >>= 1) p += __shfl_down(p, off);
        if (lane == 0) ((float*)outbuf)[w] = p + bfc[0];
    }
}

extern "C" void kernel_launch(void* const* d_in, const int* in_sizes, int n_in,
                              void* d_out, int out_size, void* d_ws, size_t ws_size,
                              hipStream_t stream) {
    const float* x   = (const float*)d_in[0];
    const float* W1  = (const float*)d_in[1];
    const float* b1  = (const float*)d_in[2];
    const float* W2  = (const float*)d_in[3];
    const float* b2  = (const float*)d_in[4];
    const float* Wfc = (const float*)d_in[5];
    const float* bfc = (const float*)d_in[6];
    const int*   src = (const int*)d_in[7];
    const int*   dst = (const int*)d_in[8];
    float* out = (float*)d_out;

    const int N = NNODES, E = NEDGES;

    // workspace layout (all offsets 16B-aligned)
    char* p = (char*)d_ws;
    float*    norm_s = (float*)p;      p += (size_t)N * 4;
    float*    norm_d = (float*)p;      p += (size_t)N * 4;
    _Float16* bufA_h = (_Float16*)p;   p += (size_t)N * NH * 2;
    _Float16* bufB_h = (_Float16*)p;   p += (size_t)N * NH * 2;
    _Float16* Wt1    = (_Float16*)p;   p += (size_t)NF * NH * 2;
    _Float16* Wt2    = (_Float16*)p;   p += (size_t)NH * NH * 2;
    float*    b1p    = (float*)p;      p += NH * 4;
    float*    b2p    = (float*)p;      p += NH * 4;
    float*    Wfcp   = (float*)p;      p += NH * 4;
    int*      cnt_out= (int*)p;        p += (size_t)N * 4;
    int*      cnt_in = (int*)p;        p += (size_t)N * 4;   // reused as cursor
    int*      row_ptr= (int*)p;        p += (size_t)(N + 1) * 4;
    int*      col    = (int*)p;        p += (size_t)E * 4;
    int*      bsum   = (int*)p;

    // ---- CSR build + norms + weight prep ----
    hipMemsetAsync(cnt_out, 0, 2 * (size_t)N * sizeof(int), stream);
    hist_kernel<<<1024, 256, 0, stream>>>(src, dst, cnt_out, cnt_in, E);
    norms_kernel<<<(N + 255) / 256, 256, 0, stream>>>(cnt_out, cnt_in, norm_s, norm_d, N);
    scanA_kernel<<<SCAN_NBLK, 256, 0, stream>>>(cnt_in, row_ptr, bsum, N);
    scanB_kernel<<<1, 64, 0, stream>>>(bsum, SCAN_NBLK, row_ptr);
    scanC_kernel<<<SCAN_NBLK, 256, 0, stream>>>(row_ptr, bsum, N);
    copy_kernel<<<(N + 255) / 256, 256, 0, stream>>>(row_ptr, cnt_in, N);
    fill_kernel<<<(E + 255) / 256, 256, 0, stream>>>(src, dst, cnt_in, col, E);
    wprep_kernel<<<(NF * NH + NH * NH + 3 * NH + 255) / 256, 256, 0, stream>>>(
        W1, W2, b1, b2, Wfc, Wt1, Wt2, b1p, b2p, Wfcp);

    const int gemm_blocks = (N + 127) / 128;
    const int gath_blocks = ((size_t)N * 64 + 255) / 256;

    // ---- layer 1: m1 = (x*ns)@W1 -> bufA_h ; h = relu(agg*nd+b1)*ns -> bufB_h
    mfma_gemm<0><<<gemm_blocks, 256, 0, stream>>>(x, Wt1, norm_s, bufA_h, N, NF);
    gatherh_kernel<0><<<gath_blocks, 256, 0, stream>>>(bufA_h, row_ptr, col, norm_d,
                                                       norm_s, b1p, nullptr, nullptr, bufB_h, N);

    // ---- layer 2: m2 = h@W2 -> bufA_h ; out = dot(agg*nd+b2, Wfc)+bfc
    mfma_gemm<1><<<gemm_blocks, 256, 0, stream>>>(bufB_h, Wt2, nullptr, bufA_h, N, NH);
    gatherh_kernel<1><<<gath_blocks, 256, 0, stream>>>(bufA_h, row_ptr, col, norm_d,
                                                       nullptr, b2p, Wfcp, bfc, out, N);
}

// Round 5
// 376.724 us; speedup vs baseline: 15.3251x; 1.2867x over previous
//
#include <hip/hip_runtime.h>
#include <hip/hip_bf16.h>

#define NNODES 100000
#define NEDGES 1600000
#define NF 256
#define NH 128
#define SCAN_ELEMS 1024
#define SCAN_NBLK ((NNODES + SCAN_ELEMS - 1) / SCAN_ELEMS)   // 98

// LDS-privatized histogram parameters
#define HG 200                     // workgroups (chunks)
#define HCHUNK (NEDGES / HG)       // 8000 edges per WG
#define HBINS 25000                // nodes per pass
#define HR 4                       // passes (4 * 25000 = 100000)
#define HWORDS (NNODES / 2)        // 50000 packed words per partial slice

typedef _Float16 half4v __attribute__((ext_vector_type(4)));
typedef _Float16 half8v __attribute__((ext_vector_type(8)));
typedef float floatx16 __attribute__((ext_vector_type(16)));

// k-permutation within each 16-block so MFMA f16 fragments (k = g*4 + (j&3) + 8*(j>>2))
// are 8 contiguous halves in storage. perm: [0,1,2,3, 8,9,10,11, 4,5,6,7, 12,13,14,15]
__device__ __forceinline__ int pos16(int k) {        // logical k (0..15) -> storage pos
    return (((k >> 2) & 1) << 3) + (k & 3) + (((k >> 3) & 1) << 2);
}
__device__ __forceinline__ int ipos16(int p) {       // storage pos -> logical k
    int g = (p >> 3) & 1, j = p & 7;
    return g * 4 + (j & 3) + ((j >> 2) << 3);
}

__device__ __forceinline__ float2 h2f2(unsigned u) {
    union { unsigned u; _Float16 h[2]; } c; c.u = u;
    return make_float2((float)c.h[0], (float)c.h[1]);
}

// ---------------- LDS-privatized degree histogram ---------------------------
// partial[g][w]: w = node>>1; byte layout: (node&1)*2 + {0:out, 1:in}
__global__ __launch_bounds__(512)
void hist_part_kernel(const int* __restrict__ src, const int* __restrict__ dst,
                      unsigned* __restrict__ partial) {
    __shared__ unsigned lds[HBINS / 2];        // 12500 words = 50 KB
    const int g = blockIdx.x, t = threadIdx.x;
    const int e0 = g * HCHUNK;
    for (int r = 0; r < HR; ++r) {
        const int lo = r * HBINS;
        for (int i = t; i < HBINS / 2; i += 512) lds[i] = 0;
        __syncthreads();
        for (int i = t; i < HCHUNK; i += 512) {
            unsigned us = (unsigned)(src[e0 + i] - lo);
            if (us < HBINS) atomicAdd(&lds[us >> 1], 1u << ((us & 1) * 16));
            unsigned ud = (unsigned)(dst[e0 + i] - lo);
            if (ud < HBINS) atomicAdd(&lds[ud >> 1], 1u << ((ud & 1) * 16 + 8));
        }
        __syncthreads();
        unsigned* dp = partial + (size_t)g * HWORDS + (lo >> 1);
        for (int i = t; i < HBINS / 2; i += 512) dp[i] = lds[i];
        __syncthreads();
    }
}

// reduce partials -> norms + cnt_in (for scan)
__global__ __launch_bounds__(256)
void hist_reduce_kernel(const unsigned* __restrict__ partial,
                        float* __restrict__ ns, float* __restrict__ nd,
                        int* __restrict__ cnt_in) {
    int w = blockIdx.x * 256 + threadIdx.x;
    if (w >= HWORDS) return;
    unsigned o0 = 0, i0 = 0, o1 = 0, i1 = 0;
    const unsigned* p = partial + w;
    #pragma unroll 4
    for (int g = 0; g < HG; ++g) {
        unsigned v = p[(size_t)g * HWORDS];
        o0 += v & 0xffu;         i0 += (v >> 8) & 0xffu;
        o1 += (v >> 16) & 0xffu; i1 += v >> 24;
    }
    int n0 = 2 * w, n1 = 2 * w + 1;
    ns[n0] = rsqrtf((float)max((int)o0, 1));
    nd[n0] = rsqrtf((float)max((int)i0, 1));
    cnt_in[n0] = (int)i0;
    ns[n1] = rsqrtf((float)max((int)o1, 1));
    nd[n1] = rsqrtf((float)max((int)i1, 1));
    cnt_in[n1] = (int)i1;
}

// ---------------- 3-pass exclusive scan over cnt_in -> row_ptr --------------
__global__ __launch_bounds__(256)
void scanA_kernel(const int* __restrict__ cnt, int* __restrict__ pre,
                  int* __restrict__ bsum, int n) {
    __shared__ int tsum[256];
    int b = blockIdx.x, t = threadIdx.x;
    int base = b * SCAN_ELEMS + t * 4;
    int v[4]; int s = 0;
    #pragma unroll
    for (int k = 0; k < 4; ++k) { int idx = base + k; v[k] = (idx < n) ? cnt[idx] : 0; s += v[k]; }
    tsum[t] = s;
    __syncthreads();
    for (int off = 1; off < 256; off <<= 1) {
        int val = (t >= off) ? tsum[t - off] : 0;
        __syncthreads();
        tsum[t] += val;
        __syncthreads();
    }
    int run = (t == 0) ? 0 : tsum[t - 1];
    #pragma unroll
    for (int k = 0; k < 4; ++k) { int idx = base + k; if (idx < n) pre[idx] = run; run += v[k]; }
    if (t == 255) bsum[b] = tsum[255];
}

__global__ __launch_bounds__(128)
void scanB_kernel(int* __restrict__ bsum, int nb, int* __restrict__ row_ptr) {
    __shared__ int s[128];
    int t = threadIdx.x;
    int v = (t < nb) ? bsum[t] : 0;
    s[t] = v;
    __syncthreads();
    for (int off = 1; off < 128; off <<= 1) {
        int u = (t >= off) ? s[t - off] : 0;
        __syncthreads();
        s[t] += u;
        __syncthreads();
    }
    if (t < nb) bsum[t] = s[t] - v;           // exclusive block sums
    if (t == 0) row_ptr[NNODES] = NEDGES;
}

// adds block offsets, finalizes row_ptr AND writes cursor copy
__global__ __launch_bounds__(256)
void scanC_kernel(int* __restrict__ pre, const int* __restrict__ bsum,
                  int* __restrict__ cursor, int n) {
    int add = bsum[blockIdx.x];
    int base = blockIdx.x * SCAN_ELEMS + threadIdx.x;
    #pragma unroll
    for (int k = 0; k < 4; ++k) {
        int idx = base + k * 256;
        if (idx < n) { int val = pre[idx] + add; pre[idx] = val; cursor[idx] = val; }
    }
}

// ---------------- bucket fill: col[pos] = src, buckets by dst ---------------
__global__ __launch_bounds__(256)
void fill_kernel(const int* __restrict__ src, const int* __restrict__ dst,
                 int* __restrict__ cursor, int* __restrict__ col, int E) {
    int i = blockIdx.x * blockDim.x + threadIdx.x;
    int stride = gridDim.x * blockDim.x;
    for (int e = i; e < E; e += stride) {
        int p = atomicAdd(&cursor[dst[e]], 1);
        col[p] = src[e];
    }
}

// ---------------- weight prep: transpose + k-permute to f16, permute vectors -
__global__ __launch_bounds__(256)
void wprep_kernel(const float* __restrict__ W1, const float* __restrict__ W2,
                  const float* __restrict__ b1, const float* __restrict__ b2,
                  const float* __restrict__ Wfc,
                  _Float16* __restrict__ Wt1, _Float16* __restrict__ Wt2,
                  float* __restrict__ b1p, float* __restrict__ b2p,
                  float* __restrict__ Wfcp) {
    int id = blockIdx.x * 256 + threadIdx.x;
    if (id < NF * NH) {                       // W1: [256][128] -> Wt1[n][perm(k)] f16
        int k = id >> 7, n = id & 127;
        Wt1[(size_t)n * NF + (k & ~15) + pos16(k & 15)] = (_Float16)W1[id];
    } else if (id < NF * NH + NH * NH) {      // W2: [128][128]
        int id2 = id - NF * NH;
        int k = id2 >> 7, n = id2 & 127;
        Wt2[(size_t)n * NH + (k & ~15) + pos16(k & 15)] = (_Float16)W2[id2];
    } else if (id < NF * NH + NH * NH + 3 * NH) {
        int id3 = id - NF * NH - NH * NH;
        int vec = id3 >> 7, pos = id3 & 127;
        int k = (pos & ~15) + ipos16(pos & 15);
        if (vec == 0) b1p[pos] = b1[k];
        else if (vec == 1) b2p[pos] = b2[k];
        else Wfcp[pos] = Wfc[k];
    }
}

// ---------------- MFMA GEMM: C = A @ W (+ row scale), f16 in/out ------------
template<int MODE>
__global__ __launch_bounds__(256)
void mfma_gemm(const void* __restrict__ Ain, const _Float16* __restrict__ Wt,
               const float* __restrict__ norm_s, _Float16* __restrict__ Cout,
               int N, int K) {
    __shared__ _Float16 As[128][40];   // 32 halves + 8 pad
    __shared__ _Float16 Bs[128][40];
    __shared__ float ns_s[128];
    const int tid = threadIdx.x;
    const int l = tid & 63, w = tid >> 6;
    const int wr = w >> 1, wc = w & 1;           // 2x2 wave grid, 64x64 per wave
    const int row0 = blockIdx.x * 128;
    if (MODE == 0 && tid < 128) {
        int gr = row0 + tid;
        ns_s[tid] = (gr < N) ? norm_s[gr] : 0.f;
    }
    floatx16 acc[2][2] = {};

    for (int k0 = 0; k0 < K; k0 += 32) {
        if (MODE == 0) {
            const float* A = (const float*)Ain;
            #pragma unroll
            for (int p = 0; p < 4; ++p) {
                int f = p * 256 + tid;
                int r = f >> 3, c4 = f & 7;
                int grow = row0 + r;
                float4 v = make_float4(0.f, 0.f, 0.f, 0.f);
                if (grow < N) v = ((const float4*)(A + (size_t)grow * K + k0))[c4];
                int base = ((c4 >> 2) << 4) + ((c4 & 1) << 3) + (((c4 >> 1) & 1) << 2);
                half4v h = { (_Float16)v.x, (_Float16)v.y, (_Float16)v.z, (_Float16)v.w };
                *(half4v*)&As[r][base] = h;
            }
        } else {
            const _Float16* A = (const _Float16*)Ain;
            #pragma unroll
            for (int p = 0; p < 2; ++p) {
                int f = p * 256 + tid;
                int r = f >> 2, c8 = f & 3;
                int grow = row0 + r;
                half8v v = {0, 0, 0, 0, 0, 0, 0, 0};
                if (grow < N) v = *(const half8v*)(A + (size_t)grow * K + k0 + c8 * 8);
                *(half8v*)&As[r][c8 * 8] = v;
            }
        }
        #pragma unroll
        for (int p = 0; p < 2; ++p) {
            int f = p * 256 + tid;
            int n = f >> 2, c8 = f & 3;
            *(half8v*)&Bs[n][c8 * 8] = *(const half8v*)(Wt + (size_t)n * K + k0 + c8 * 8);
        }
        __syncthreads();
        #pragma unroll
        for (int kk = 0; kk < 2; ++kk) {
            half8v a[2], b[2];
            #pragma unroll
            for (int m = 0; m < 2; ++m)
                a[m] = *(const half8v*)&As[wr * 64 + m * 32 + (l & 31)][kk * 16 + (l >> 5) * 8];
            #pragma unroll
            for (int n = 0; n < 2; ++n)
                b[n] = *(const half8v*)&Bs[wc * 64 + n * 32 + (l & 31)][kk * 16 + (l >> 5) * 8];
            #pragma unroll
            for (int m = 0; m < 2; ++m)
                #pragma unroll
                for (int n = 0; n < 2; ++n)
                    acc[m][n] = __builtin_amdgcn_mfma_f32_32x32x16_f16(a[m], b[n], acc[m][n], 0, 0, 0);
        }
        __syncthreads();
    }

    const int cpos = pos16(l & 15);
    const int chi = ((l >> 4) & 1) << 4;
    #pragma unroll
    for (int m = 0; m < 2; ++m) {
        #pragma unroll
        for (int r = 0; r < 16; ++r) {
            int rloc = wr * 64 + m * 32 + (r & 3) + ((r >> 2) << 3) + ((l >> 5) << 2);
            int grow = row0 + rloc;
            if (grow < N) {
                float s = (MODE == 0) ? ns_s[rloc] : 1.0f;
                #pragma unroll
                for (int n = 0; n < 2; ++n) {
                    int colbase = wc * 64 + n * 32 + chi;
                    Cout[(size_t)grow * NH + colbase + cpos] = (_Float16)(acc[m][n][r] * s);
                }
            }
        }
    }
}

// ---------------- CSR gather over f16 perm-order rows, one wave per node ----
template<int FUSED>
__global__ __launch_bounds__(256)
void gatherh_kernel(const _Float16* __restrict__ m, const int* __restrict__ row_ptr,
                    const int* __restrict__ col, const float* __restrict__ norm_d,
                    const float* __restrict__ norm_s, const float* __restrict__ bvp,
                    const float* __restrict__ Wfcp, const float* __restrict__ bfc,
                    void* __restrict__ outbuf, int N) {
    int w = (blockIdx.x * 256 + threadIdx.x) >> 6;
    int lane = threadIdx.x & 63;
    if (w >= N) return;
    int beg = row_ptr[w], end = row_ptr[w + 1];
    const unsigned* mu = (const unsigned*)m;     // 64 uints (128 halves) per row
    float ax = 0.f, ay = 0.f;
    int i = beg;
    for (; i + 3 < end; i += 4) {
        unsigned u0 = mu[(size_t)col[i]     * 64 + lane];
        unsigned u1 = mu[(size_t)col[i + 1] * 64 + lane];
        unsigned u2 = mu[(size_t)col[i + 2] * 64 + lane];
        unsigned u3 = mu[(size_t)col[i + 3] * 64 + lane];
        float2 v0 = h2f2(u0), v1 = h2f2(u1), v2 = h2f2(u2), v3 = h2f2(u3);
        ax += (v0.x + v1.x) + (v2.x + v3.x);
        ay += (v0.y + v1.y) + (v2.y + v3.y);
    }
    for (; i < end; ++i) {
        float2 v = h2f2(mu[(size_t)col[i] * 64 + lane]);
        ax += v.x; ay += v.y;
    }
    float nd = norm_d[w];
    float2 bv = ((const float2*)bvp)[lane];
    if (FUSED == 0) {
        float ns = norm_s[w];
        float hx = fmaxf(fmaf(ax, nd, bv.x), 0.f) * ns;
        float hy = fmaxf(fmaf(ay, nd, bv.y), 0.f) * ns;
        union { unsigned u; _Float16 h[2]; } c;
        c.h[0] = (_Float16)hx; c.h[1] = (_Float16)hy;
        ((unsigned*)outbuf)[(size_t)w * 64 + lane] = c.u;
    } else {
        float2 wf = ((const float2*)Wfcp)[lane];
        float p = fmaf(ax, nd, bv.x) * wf.x + fmaf(ay, nd, bv.y) * wf.y;
        #pragma unroll
        for (int off = 32; off > 0; off >>= 1) p += __shfl_down(p, off);
        if (lane == 0) ((float*)outbuf)[w] = p + bfc[0];
    }
}

extern "C" void kernel_launch(void* const* d_in, const int* in_sizes, int n_in,
                              void* d_out, int out_size, void* d_ws, size_t ws_size,
                              hipStream_t stream) {
    const float* x   = (const float*)d_in[0];
    const float* W1  = (const float*)d_in[1];
    const float* b1  = (const float*)d_in[2];
    const float* W2  = (const float*)d_in[3];
    const float* b2  = (const float*)d_in[4];
    const float* Wfc = (const float*)d_in[5];
    const float* bfc = (const float*)d_in[6];
    const int*   src = (const int*)d_in[7];
    const int*   dst = (const int*)d_in[8];
    float* out = (float*)d_out;

    const int N = NNODES, E = NEDGES;

    // workspace layout (all offsets 16B-aligned)
    char* p = (char*)d_ws;
    float*    norm_s = (float*)p;      p += (size_t)N * 4;
    float*    norm_d = (float*)p;      p += (size_t)N * 4;
    _Float16* bufA_h = (_Float16*)p;   p += (size_t)N * NH * 2;
    _Float16* bufB_h = (_Float16*)p;   p += (size_t)N * NH * 2;
    _Float16* Wt1    = (_Float16*)p;   p += (size_t)NF * NH * 2;
    _Float16* Wt2    = (_Float16*)p;   p += (size_t)NH * NH * 2;
    float*    b1p    = (float*)p;      p += NH * 4;
    float*    b2p    = (float*)p;      p += NH * 4;
    float*    Wfcp   = (float*)p;      p += NH * 4;
    int*      cnt_in = (int*)p;        p += (size_t)N * 4;
    int*      cursor = (int*)p;        p += (size_t)N * 4;
    int*      row_ptr= (int*)p;        p += (size_t)(N + 1) * 4 + 12;  // keep 16B align
    int*      col    = (int*)p;        p += (size_t)E * 4;
    int*      bsum   = (int*)p;        p += 128 * 4;
    unsigned* partial= (unsigned*)p;   // HG * HWORDS * 4 = 40 MB

    // ---- CSR build + norms + weight prep (no global atomics except fill) ----
    hist_part_kernel<<<HG, 512, 0, stream>>>(src, dst, partial);
    hist_reduce_kernel<<<(HWORDS + 255) / 256, 256, 0, stream>>>(partial, norm_s, norm_d, cnt_in);
    scanA_kernel<<<SCAN_NBLK, 256, 0, stream>>>(cnt_in, row_ptr, bsum, N);
    scanB_kernel<<<1, 128, 0, stream>>>(bsum, SCAN_NBLK, row_ptr);
    scanC_kernel<<<SCAN_NBLK, 256, 0, stream>>>(row_ptr, bsum, cursor, N);
    fill_kernel<<<(E + 255) / 256, 256, 0, stream>>>(src, dst, cursor, col, E);
    wprep_kernel<<<(NF * NH + NH * NH + 3 * NH + 255) / 256, 256, 0, stream>>>(
        W1, W2, b1, b2, Wfc, Wt1, Wt2, b1p, b2p, Wfcp);

    const int gemm_blocks = (N + 127) / 128;
    const int gath_blocks = ((size_t)N * 64 + 255) / 256;

    // ---- layer 1: m1 = (x*ns)@W1 -> bufA_h ; h = relu(agg*nd+b1)*ns -> bufB_h
    mfma_gemm<0><<<gemm_blocks, 256, 0, stream>>>(x, Wt1, norm_s, bufA_h, N, NF);
    gatherh_kernel<0><<<gath_blocks, 256, 0, stream>>>(bufA_h, row_ptr, col, norm_d,
                                                       norm_s, b1p, nullptr, nullptr, bufB_h, N);

    // ---- layer 2: m2 = h@W2 -> bufA_h ; out = dot(agg*nd+b2, Wfc)+bfc
    mfma_gemm<1><<<gemm_blocks, 256, 0, stream>>>(bufB_h, Wt2, nullptr, bufA_h, N, NH);
    gatherh_kernel<1><<<gath_blocks, 256, 0, stream>>>(bufA_h, row_ptr, col, norm_d,
                                                       nullptr, b2p, Wfcp, bfc, out, N);
}

// Round 6
// 342.857 us; speedup vs baseline: 16.8389x; 1.0988x over previous
//
#include <hip/hip_runtime.h>
#include <hip/hip_bf16.h>

#define NNODES 100000
#define NEDGES 1600000
#define NF 256
#define NH 128
#define SCAN_ELEMS 1024
#define SCAN_NBLK ((NNODES + SCAN_ELEMS - 1) / SCAN_ELEMS)   // 98

// LDS-privatized histogram / fill parameters
#define HG 200                     // workgroups (chunks)
#define HCHUNK (NEDGES / HG)       // 8000 edges per WG
#define HBINS 25000                // nodes per pass
#define HR 4                       // passes (4 * 25000 = 100000)
#define HWORDS (NNODES / 2)        // 50000 packed words per partial slice

typedef _Float16 half4v __attribute__((ext_vector_type(4)));
typedef _Float16 half8v __attribute__((ext_vector_type(8)));
typedef float floatx16 __attribute__((ext_vector_type(16)));

// k-permutation within each 16-block so MFMA f16 fragments (k = g*4 + (j&3) + 8*(j>>2))
// are 8 contiguous halves in storage. perm: [0,1,2,3, 8,9,10,11, 4,5,6,7, 12,13,14,15]
__device__ __forceinline__ int pos16(int k) {        // logical k (0..15) -> storage pos
    return (((k >> 2) & 1) << 3) + (k & 3) + (((k >> 3) & 1) << 2);
}
__device__ __forceinline__ int ipos16(int p) {       // storage pos -> logical k
    int g = (p >> 3) & 1, j = p & 7;
    return g * 4 + (j & 3) + ((j >> 2) << 3);
}

__device__ __forceinline__ float2 h2f2(unsigned u) {
    union { unsigned u; _Float16 h[2]; } c; c.u = u;
    return make_float2((float)c.h[0], (float)c.h[1]);
}

// ---------------- LDS-privatized degree histogram ---------------------------
// partial[g][w]: w = node>>1; byte layout: b0=out(n0) b1=in(n0) b2=out(n1) b3=in(n1)
__global__ __launch_bounds__(512)
void hist_part_kernel(const int* __restrict__ src, const int* __restrict__ dst,
                      unsigned* __restrict__ partial) {
    __shared__ unsigned lds[HBINS / 2];        // 12500 words = 50 KB
    const int g = blockIdx.x, t = threadIdx.x;
    const int e0 = g * HCHUNK;
    for (int r = 0; r < HR; ++r) {
        const int lo = r * HBINS;
        for (int i = t; i < HBINS / 2; i += 512) lds[i] = 0;
        __syncthreads();
        for (int i = t; i < HCHUNK; i += 512) {
            unsigned us = (unsigned)(src[e0 + i] - lo);
            if (us < HBINS) atomicAdd(&lds[us >> 1], 1u << ((us & 1) * 16));
            unsigned ud = (unsigned)(dst[e0 + i] - lo);
            if (ud < HBINS) atomicAdd(&lds[ud >> 1], 1u << ((ud & 1) * 16 + 8));
        }
        __syncthreads();
        unsigned* dp = partial + (size_t)g * HWORDS + (lo >> 1);
        for (int i = t; i < HBINS / 2; i += 512) dp[i] = lds[i];
        __syncthreads();
    }
}

// reduce partials -> norms + cnt_in (for scan)
__global__ __launch_bounds__(256)
void hist_reduce_kernel(const unsigned* __restrict__ partial,
                        float* __restrict__ ns, float* __restrict__ nd,
                        int* __restrict__ cnt_in) {
    int w = blockIdx.x * 256 + threadIdx.x;
    if (w >= HWORDS) return;
    unsigned o0 = 0, i0 = 0, o1 = 0, i1 = 0;
    const unsigned* p = partial + w;
    #pragma unroll 4
    for (int g = 0; g < HG; ++g) {
        unsigned v = p[(size_t)g * HWORDS];
        o0 += v & 0xffu;         i0 += (v >> 8) & 0xffu;
        o1 += (v >> 16) & 0xffu; i1 += v >> 24;
    }
    int n0 = 2 * w, n1 = 2 * w + 1;
    ns[n0] = rsqrtf((float)max((int)o0, 1));
    nd[n0] = rsqrtf((float)max((int)i0, 1));
    cnt_in[n0] = (int)i0;
    ns[n1] = rsqrtf((float)max((int)o1, 1));
    nd[n1] = rsqrtf((float)max((int)i1, 1));
    cnt_in[n1] = (int)i1;
}

// exclusive scan of per-chunk in-degree across chunks -> byte offsets
// offb[g][node] = sum_{g'<g} in_cnt[g'][node]  (total in-degree << 255)
__global__ __launch_bounds__(256)
void chunk_scan_kernel(const unsigned* __restrict__ partial,
                       unsigned char* __restrict__ offb) {
    int w = blockIdx.x * 256 + threadIdx.x;
    if (w >= HWORDS) return;
    unsigned run0 = 0, run1 = 0;
    for (int g = 0; g < HG; ++g) {
        unsigned v = partial[(size_t)g * HWORDS + w];
        unsigned char* ob = offb + (size_t)g * NNODES;
        ob[2 * w]     = (unsigned char)run0;
        ob[2 * w + 1] = (unsigned char)run1;
        run0 += (v >> 8) & 0xffu;
        run1 += v >> 24;
    }
}

// ---------------- 3-pass exclusive scan over cnt_in -> row_ptr --------------
__global__ __launch_bounds__(256)
void scanA_kernel(const int* __restrict__ cnt, int* __restrict__ pre,
                  int* __restrict__ bsum, int n) {
    __shared__ int tsum[256];
    int b = blockIdx.x, t = threadIdx.x;
    int base = b * SCAN_ELEMS + t * 4;
    int v[4]; int s = 0;
    #pragma unroll
    for (int k = 0; k < 4; ++k) { int idx = base + k; v[k] = (idx < n) ? cnt[idx] : 0; s += v[k]; }
    tsum[t] = s;
    __syncthreads();
    for (int off = 1; off < 256; off <<= 1) {
        int val = (t >= off) ? tsum[t - off] : 0;
        __syncthreads();
        tsum[t] += val;
        __syncthreads();
    }
    int run = (t == 0) ? 0 : tsum[t - 1];
    #pragma unroll
    for (int k = 0; k < 4; ++k) { int idx = base + k; if (idx < n) pre[idx] = run; run += v[k]; }
    if (t == 255) bsum[b] = tsum[255];
}

__global__ __launch_bounds__(128)
void scanB_kernel(int* __restrict__ bsum, int nb, int* __restrict__ row_ptr) {
    __shared__ int s[128];
    int t = threadIdx.x;
    int v = (t < nb) ? bsum[t] : 0;
    s[t] = v;
    __syncthreads();
    for (int off = 1; off < 128; off <<= 1) {
        int u = (t >= off) ? s[t - off] : 0;
        __syncthreads();
        s[t] += u;
        __syncthreads();
    }
    if (t < nb) bsum[t] = s[t] - v;           // exclusive block sums
    if (t == 0) row_ptr[NNODES] = NEDGES;
}

__global__ __launch_bounds__(256)
void scanC_kernel(int* __restrict__ pre, const int* __restrict__ bsum, int n) {
    int add = bsum[blockIdx.x];
    int base = blockIdx.x * SCAN_ELEMS + threadIdx.x;
    #pragma unroll
    for (int k = 0; k < 4; ++k) {
        int idx = base + k * 256;
        if (idx < n) pre[idx] += add;
    }
}

// ---------------- atomic-free bucket fill -----------------------------------
// WG g replays chunk g through the same 4 windows; intra-chunk rank from an
// LDS packed counter; position = row_ptr[d] + offb[g][d] + rank. Plain store.
__global__ __launch_bounds__(512)
void fill_kernel(const int* __restrict__ src, const int* __restrict__ dst,
                 const int* __restrict__ row_ptr, const unsigned char* __restrict__ offb,
                 int* __restrict__ col) {
    __shared__ unsigned lcur[HBINS / 2];       // 12500 words, 2x16-bit counters
    const int g = blockIdx.x, t = threadIdx.x;
    const int e0 = g * HCHUNK;
    const unsigned char* ob = offb + (size_t)g * NNODES;
    for (int r = 0; r < HR; ++r) {
        const int lo = r * HBINS;
        for (int i = t; i < HBINS / 2; i += 512) lcur[i] = 0;
        __syncthreads();
        for (int i = t; i < HCHUNK; i += 512) {
            int d = dst[e0 + i];
            unsigned ud = (unsigned)(d - lo);
            if (ud < HBINS) {
                unsigned prev = atomicAdd(&lcur[ud >> 1], 1u << ((ud & 1) * 16));
                unsigned rank = (prev >> ((ud & 1) * 16)) & 0xffffu;
                int p = row_ptr[d] + (int)ob[d] + (int)rank;
                col[p] = src[e0 + i];
            }
        }
        __syncthreads();
    }
}

// ---------------- weight prep: transpose + k-permute to f16, permute vectors -
__global__ __launch_bounds__(256)
void wprep_kernel(const float* __restrict__ W1, const float* __restrict__ W2,
                  const float* __restrict__ b1, const float* __restrict__ b2,
                  const float* __restrict__ Wfc,
                  _Float16* __restrict__ Wt1, _Float16* __restrict__ Wt2,
                  float* __restrict__ b1p, float* __restrict__ b2p,
                  float* __restrict__ Wfcp) {
    int id = blockIdx.x * 256 + threadIdx.x;
    if (id < NF * NH) {                       // W1: [256][128] -> Wt1[n][perm(k)] f16
        int k = id >> 7, n = id & 127;
        Wt1[(size_t)n * NF + (k & ~15) + pos16(k & 15)] = (_Float16)W1[id];
    } else if (id < NF * NH + NH * NH) {      // W2: [128][128]
        int id2 = id - NF * NH;
        int k = id2 >> 7, n = id2 & 127;
        Wt2[(size_t)n * NH + (k & ~15) + pos16(k & 15)] = (_Float16)W2[id2];
    } else if (id < NF * NH + NH * NH + 3 * NH) {
        int id3 = id - NF * NH - NH * NH;
        int vec = id3 >> 7, pos = id3 & 127;
        int k = (pos & ~15) + ipos16(pos & 15);
        if (vec == 0) b1p[pos] = b1[k];
        else if (vec == 1) b2p[pos] = b2[k];
        else Wfcp[pos] = Wfc[k];
    }
}

// ---------------- MFMA GEMM: C = A @ W (+ row scale), f16 in/out ------------
template<int MODE>
__global__ __launch_bounds__(256)
void mfma_gemm(const void* __restrict__ Ain, const _Float16* __restrict__ Wt,
               const float* __restrict__ norm_s, _Float16* __restrict__ Cout,
               int N, int K) {
    __shared__ _Float16 As[128][40];   // 32 halves + 8 pad
    __shared__ _Float16 Bs[128][40];
    __shared__ float ns_s[128];
    const int tid = threadIdx.x;
    const int l = tid & 63, w = tid >> 6;
    const int wr = w >> 1, wc = w & 1;           // 2x2 wave grid, 64x64 per wave
    const int row0 = blockIdx.x * 128;
    if (MODE == 0 && tid < 128) {
        int gr = row0 + tid;
        ns_s[tid] = (gr < N) ? norm_s[gr] : 0.f;
    }
    floatx16 acc[2][2] = {};

    for (int k0 = 0; k0 < K; k0 += 32) {
        if (MODE == 0) {
            const float* A = (const float*)Ain;
            #pragma unroll
            for (int p = 0; p < 4; ++p) {
                int f = p * 256 + tid;
                int r = f >> 3, c4 = f & 7;
                int grow = row0 + r;
                float4 v = make_float4(0.f, 0.f, 0.f, 0.f);
                if (grow < N) v = ((const float4*)(A + (size_t)grow * K + k0))[c4];
                int base = ((c4 >> 2) << 4) + ((c4 & 1) << 3) + (((c4 >> 1) & 1) << 2);
                half4v h = { (_Float16)v.x, (_Float16)v.y, (_Float16)v.z, (_Float16)v.w };
                *(half4v*)&As[r][base] = h;
            }
        } else {
            const _Float16* A = (const _Float16*)Ain;
            #pragma unroll
            for (int p = 0; p < 2; ++p) {
                int f = p * 256 + tid;
                int r = f >> 2, c8 = f & 3;
                int grow = row0 + r;
                half8v v = {0, 0, 0, 0, 0, 0, 0, 0};
                if (grow < N) v = *(const half8v*)(A + (size_t)grow * K + k0 + c8 * 8);
                *(half8v*)&As[r][c8 * 8] = v;
            }
        }
        #pragma unroll
        for (int p = 0; p < 2; ++p) {
            int f = p * 256 + tid;
            int n = f >> 2, c8 = f & 3;
            *(half8v*)&Bs[n][c8 * 8] = *(const half8v*)(Wt + (size_t)n * K + k0 + c8 * 8);
        }
        __syncthreads();
        #pragma unroll
        for (int kk = 0; kk < 2; ++kk) {
            half8v a[2], b[2];
            #pragma unroll
            for (int m = 0; m < 2; ++m)
                a[m] = *(const half8v*)&As[wr * 64 + m * 32 + (l & 31)][kk * 16 + (l >> 5) * 8];
            #pragma unroll
            for (int n = 0; n < 2; ++n)
                b[n] = *(const half8v*)&Bs[wc * 64 + n * 32 + (l & 31)][kk * 16 + (l >> 5) * 8];
            #pragma unroll
            for (int m = 0; m < 2; ++m)
                #pragma unroll
                for (int n = 0; n < 2; ++n)
                    acc[m][n] = __builtin_amdgcn_mfma_f32_32x32x16_f16(a[m], b[n], acc[m][n], 0, 0, 0);
        }
        __syncthreads();
    }

    const int cpos = pos16(l & 15);
    const int chi = ((l >> 4) & 1) << 4;
    #pragma unroll
    for (int m = 0; m < 2; ++m) {
        #pragma unroll
        for (int r = 0; r < 16; ++r) {
            int rloc = wr * 64 + m * 32 + (r & 3) + ((r >> 2) << 3) + ((l >> 5) << 2);
            int grow = row0 + rloc;
            if (grow < N) {
                float s = (MODE == 0) ? ns_s[rloc] : 1.0f;
                #pragma unroll
                for (int n = 0; n < 2; ++n) {
                    int colbase = wc * 64 + n * 32 + chi;
                    Cout[(size_t)grow * NH + colbase + cpos] = (_Float16)(acc[m][n][r] * s);
                }
            }
        }
    }
}

// ---------------- CSR gather over f16 perm-order rows, one wave per node ----
template<int FUSED>
__global__ __launch_bounds__(256)
void gatherh_kernel(const _Float16* __restrict__ m, const int* __restrict__ row_ptr,
                    const int* __restrict__ col, const float* __restrict__ norm_d,
                    const float* __restrict__ norm_s, const float* __restrict__ bvp,
                    const float* __restrict__ Wfcp, const float* __restrict__ bfc,
                    void* __restrict__ outbuf, int N) {
    int w = (blockIdx.x * 256 + threadIdx.x) >> 6;
    int lane = threadIdx.x & 63;
    if (w >= N) return;
    int beg = row_ptr[w], end = row_ptr[w + 1];
    const unsigned* mu = (const unsigned*)m;     // 64 uints (128 halves) per row
    float ax = 0.f, ay = 0.f;
    int i = beg;
    for (; i + 3 < end; i += 4) {
        unsigned u0 = mu[(size_t)col[i]     * 64 + lane];
        unsigned u1 = mu[(size_t)col[i + 1] * 64 + lane];
        unsigned u2 = mu[(size_t)col[i + 2] * 64 + lane];
        unsigned u3 = mu[(size_t)col[i + 3] * 64 + lane];
        float2 v0 = h2f2(u0), v1 = h2f2(u1), v2 = h2f2(u2), v3 = h2f2(u3);
        ax += (v0.x + v1.x) + (v2.x + v3.x);
        ay += (v0.y + v1.y) + (v2.y + v3.y);
    }
    for (; i < end; ++i) {
        float2 v = h2f2(mu[(size_t)col[i] * 64 + lane]);
        ax += v.x; ay += v.y;
    }
    float nd = norm_d[w];
    float2 bv = ((const float2*)bvp)[lane];
    if (FUSED == 0) {
        float ns = norm_s[w];
        float hx = fmaxf(fmaf(ax, nd, bv.x), 0.f) * ns;
        float hy = fmaxf(fmaf(ay, nd, bv.y), 0.f) * ns;
        union { unsigned u; _Float16 h[2]; } c;
        c.h[0] = (_Float16)hx; c.h[1] = (_Float16)hy;
        ((unsigned*)outbuf)[(size_t)w * 64 + lane] = c.u;
    } else {
        float2 wf = ((const float2*)Wfcp)[lane];
        float p = fmaf(ax, nd, bv.x) * wf.x + fmaf(ay, nd, bv.y) * wf.y;
        #pragma unroll
        for (int off = 32; off > 0; off >>= 1) p += __shfl_down(p, off);
        if (lane == 0) ((float*)outbuf)[w] = p + bfc[0];
    }
}

extern "C" void kernel_launch(void* const* d_in, const int* in_sizes, int n_in,
                              void* d_out, int out_size, void* d_ws, size_t ws_size,
                              hipStream_t stream) {
    const float* x   = (const float*)d_in[0];
    const float* W1  = (const float*)d_in[1];
    const float* b1  = (const float*)d_in[2];
    const float* W2  = (const float*)d_in[3];
    const float* b2  = (const float*)d_in[4];
    const float* Wfc = (const float*)d_in[5];
    const float* bfc = (const float*)d_in[6];
    const int*   src = (const int*)d_in[7];
    const int*   dst = (const int*)d_in[8];
    float* out = (float*)d_out;

    const int N = NNODES, E = NEDGES;

    // workspace layout (all offsets 16B-aligned)
    char* p = (char*)d_ws;
    float*    norm_s = (float*)p;      p += (size_t)N * 4;
    float*    norm_d = (float*)p;      p += (size_t)N * 4;
    _Float16* bufA_h = (_Float16*)p;   p += (size_t)N * NH * 2;
    _Float16* bufB_h = (_Float16*)p;   p += (size_t)N * NH * 2;
    _Float16* Wt1    = (_Float16*)p;   p += (size_t)NF * NH * 2;
    _Float16* Wt2    = (_Float16*)p;   p += (size_t)NH * NH * 2;
    float*    b1p    = (float*)p;      p += NH * 4;
    float*    b2p    = (float*)p;      p += NH * 4;
    float*    Wfcp   = (float*)p;      p += NH * 4;
    int*      cnt_in = (int*)p;        p += (size_t)N * 4;
    int*      row_ptr= (int*)p;        p += (size_t)(N + 1) * 4 + 12;  // keep 16B align
    int*      col    = (int*)p;        p += (size_t)E * 4;
    int*      bsum   = (int*)p;        p += 128 * 4;
    unsigned* partial= (unsigned*)p;   // HG * HWORDS * 4 = 40 MB
    // offb (HG * NNODES = 20 MB) aliases bufA_h/bufB_h (51.2 MB): dead before
    // mfma_gemm<0> first writes bufA_h, and fill completes before that launch.
    unsigned char* offb = (unsigned char*)bufA_h;

    // ---- CSR build + norms + weight prep (zero global atomics) ----
    hist_part_kernel<<<HG, 512, 0, stream>>>(src, dst, partial);
    hist_reduce_kernel<<<(HWORDS + 255) / 256, 256, 0, stream>>>(partial, norm_s, norm_d, cnt_in);
    chunk_scan_kernel<<<(HWORDS + 255) / 256, 256, 0, stream>>>(partial, offb);
    scanA_kernel<<<SCAN_NBLK, 256, 0, stream>>>(cnt_in, row_ptr, bsum, N);
    scanB_kernel<<<1, 128, 0, stream>>>(bsum, SCAN_NBLK, row_ptr);
    scanC_kernel<<<SCAN_NBLK, 256, 0, stream>>>(row_ptr, bsum, N);
    fill_kernel<<<HG, 512, 0, stream>>>(src, dst, row_ptr, offb, col);
    wprep_kernel<<<(NF * NH + NH * NH + 3 * NH + 255) / 256, 256, 0, stream>>>(
        W1, W2, b1, b2, Wfc, Wt1, Wt2, b1p, b2p, Wfcp);

    const int gemm_blocks = (N + 127) / 128;
    const int gath_blocks = ((size_t)N * 64 + 255) / 256;

    // ---- layer 1: m1 = (x*ns)@W1 -> bufA_h ; h = relu(agg*nd+b1)*ns -> bufB_h
    mfma_gemm<0><<<gemm_blocks, 256, 0, stream>>>(x, Wt1, norm_s, bufA_h, N, NF);
    gatherh_kernel<0><<<gath_blocks, 256, 0, stream>>>(bufA_h, row_ptr, col, norm_d,
                                                       norm_s, b1p, nullptr, nullptr, bufB_h, N);

    // ---- layer 2: m2 = h@W2 -> bufA_h ; out = dot(agg*nd+b2, Wfc)+bfc
    mfma_gemm<1><<<gemm_blocks, 256, 0, stream>>>(bufB_h, Wt2, nullptr, bufA_h, N, NH);
    gatherh_kernel<1><<<gath_blocks, 256, 0, stream>>>(bufA_h, row_ptr, col, norm_d,
                                                       nullptr, b2p, Wfcp, bfc, out, N);
}